// Round 9
// baseline (604.349 us; speedup 1.0000x reference)
//
#include <hip/hip_runtime.h>

// GCN 2-layer forward on MI355X (R9):
//   CSR build: atomic-FREE two-level bucket partition (R8 showed global
//   returning atomics are throughput-capped ~12G/s and cross-XCD writes
//   amplify 8x; more MLP/TLP did nothing).
//   Hb  = bf16( Y@W1 )   LDS-staged MFMA GEMM, 3-product
//   HA' = relu(spmm(A,Hb)) -> [HAh|HAl]
//   Gb  = bf16( HA@W2 );  out = spmm(A,Gb)

#define NN 50000
#define NBUCKET 256
#define RPB 196          // rows per bucket (256*196 >= 50000)
#define PBLK 782         // partition blocks (782*1024 >= 800000 edges)

typedef short s8v __attribute__((ext_vector_type(8)));  // 8 bf16 in 4 VGPRs
typedef float f4v __attribute__((ext_vector_type(4)));
typedef unsigned int u32;

// ---------------- bf16 helpers ----------------

__device__ inline unsigned int bf16_rne_bits(float x) {
    unsigned int u = __float_as_uint(x);
    return (u + 0x7FFFu + ((u >> 16) & 1u)) >> 16;  // round-to-nearest-even
}
__device__ inline float bf16_bits_to_f32(unsigned int h) {
    return __uint_as_float(h << 16);
}
__device__ inline void split_hi_lo(float x, unsigned short& hi, unsigned short& lo) {
    unsigned int h = bf16_rne_bits(x);
    hi = (unsigned short)h;
    lo = (unsigned short)bf16_rne_bits(x - bf16_bits_to_f32(h));
}
__device__ inline void unpack2(unsigned int u, float& f0, float& f1) {
    f0 = __uint_as_float(u << 16);
    f1 = __uint_as_float(u & 0xFFFF0000u);
}

__device__ inline void gl_lds16(const void* g, void* l) {
    __builtin_amdgcn_global_load_lds(
        (const __attribute__((address_space(1))) u32*)g,
        (__attribute__((address_space(3))) u32*)l, 16, 0, 0);
}

// ---------------- CSR build: bucket partition (no global atomics) ----------------

// Per-block LDS histogram over 256 row-buckets -> cnt2d[bin][block].
__global__ __launch_bounds__(256) void bucket_hist(const int* __restrict__ erow,
                                                   int* __restrict__ cnt2d, int E) {
    __shared__ int h[NBUCKET];
    const int t = threadIdx.x, blk = blockIdx.x;
    h[t] = 0;
    __syncthreads();
#pragma unroll
    for (int u = 0; u < 4; ++u) {
        int i = blk * 1024 + u * 256 + t;
        if (i < E) atomicAdd(&h[erow[i] / RPB], 1);
    }
    __syncthreads();
    cnt2d[t * PBLK + blk] = h[t];
}

// In-place exclusive scan of cnt2d (bin-major, NBUCKET*PBLK elems);
// emits bucket_base[] and row_ptr[N]=E.
__global__ __launch_bounds__(1024) void bucket_scan(int* __restrict__ cnt2d,
                                                    int* __restrict__ bucket_base,
                                                    int* __restrict__ row_ptr,
                                                    int n, int E) {
    __shared__ int lds[1024];
    const int TOT = NBUCKET * PBLK;
    const int t = threadIdx.x;
    const int chunk = (TOT + 1023) / 1024;
    int lo = t * chunk, hi = min(TOT, lo + chunk);
    int s = 0;
    for (int i = lo; i < hi; ++i) s += cnt2d[i];
    lds[t] = s;
    __syncthreads();
    for (int off = 1; off < 1024; off <<= 1) {
        int v = (t >= off) ? lds[t - off] : 0;
        __syncthreads();
        lds[t] += v;
        __syncthreads();
    }
    int run = lds[t] - s;  // exclusive prefix
    for (int i = lo; i < hi; ++i) {
        int c = cnt2d[i];
        cnt2d[i] = run;
        run += c;
    }
    __syncthreads();
    if (t < NBUCKET) bucket_base[t] = cnt2d[t * PBLK];
    if (t == 0) {
        bucket_base[NBUCKET] = E;
        row_ptr[n] = E;
    }
}

// Partition edges into bucket-contiguous brow/bcv using LDS cursors seeded
// from the scanned bases. No global atomics.
__global__ __launch_bounds__(256) void bucket_scatter(const int* __restrict__ erow,
                                                      const int* __restrict__ ecol,
                                                      const float* __restrict__ eval_,
                                                      const int* __restrict__ base2d,
                                                      int* __restrict__ brow,
                                                      int2* __restrict__ bcv, int E) {
    __shared__ int cur[NBUCKET];
    const int t = threadIdx.x, blk = blockIdx.x;
    cur[t] = base2d[t * PBLK + blk];
    __syncthreads();
#pragma unroll
    for (int u = 0; u < 4; ++u) {
        int i = blk * 1024 + u * 256 + t;
        if (i < E) {
            int r = erow[i];
            int pos = atomicAdd(&cur[r / RPB], 1);  // LDS atomic
            brow[pos] = r;
            bcv[pos] = make_int2(ecol[i], __float_as_int(eval_[i]));
        }
    }
}

// One block per bucket: LDS hist -> LDS scan -> row_ptr slice + meta scatter.
// All meta writes land in this bucket's contiguous ~25KB slice (one XCD).
__global__ __launch_bounds__(256) void bucket_build(const int* __restrict__ brow,
                                                    const int2* __restrict__ bcv,
                                                    const int* __restrict__ bucket_base,
                                                    int* __restrict__ row_ptr,
                                                    int2* __restrict__ meta, int n) {
    __shared__ int h[256];
    __shared__ int cur[256];
    const int t = threadIdx.x, b = blockIdx.x;
    const int s = bucket_base[b];
    const int e = bucket_base[b + 1];
    const int row0 = b * RPB;
    h[t] = 0;
    __syncthreads();
    for (int i = s + t; i < e; i += 256) atomicAdd(&h[brow[i] - row0], 1);
    __syncthreads();
    int v = h[t];
    for (int off = 1; off < 256; off <<= 1) {
        int a = (t >= off) ? h[t - off] : 0;
        __syncthreads();
        h[t] += a;
        __syncthreads();
    }
    int rp = s + h[t] - v;  // global exclusive position for row row0+t
    int grow = row0 + t;
    if (t < RPB && grow < n) row_ptr[grow] = rp;
    cur[t] = rp;
    __syncthreads();
    for (int i = s + t; i < e; i += 256) {
        int pos = atomicAdd(&cur[brow[i] - row0], 1);  // LDS atomic
        meta[pos] = bcv[i];
    }
}

// ---------------- split passes ----------------

// Y [M][256] f32 -> Y' [M][512] bf16 = [Yh(256) | Yl(256)]
__global__ __launch_bounds__(256) void split_kernel(const float* __restrict__ X,
                                                    unsigned short* __restrict__ Xp, int n4) {
    int i = blockIdx.x * blockDim.x + threadIdx.x;
    int stride = gridDim.x * blockDim.x;
    for (; i < n4; i += stride) {
        float4 v = reinterpret_cast<const float4*>(X)[i];
        ushort4 h, l;
        split_hi_lo(v.x, h.x, l.x);
        split_hi_lo(v.y, h.y, l.y);
        split_hi_lo(v.z, h.z, l.z);
        split_hi_lo(v.w, h.w, l.w);
        int row = i >> 6, c4 = (i & 63) * 4;
        *reinterpret_cast<ushort4*>(Xp + (size_t)row * 512 + c4) = h;
        *reinterpret_cast<ushort4*>(Xp + (size_t)row * 512 + 256 + c4) = l;
    }
}

// W [K=256][N] f32 -> Bth, Btl  [N][256] bf16 (transposed hi / lo)
__global__ __launch_bounds__(256) void wsplit_kernel(const float* __restrict__ W,
                                                     unsigned short* __restrict__ Bth,
                                                     unsigned short* __restrict__ Btl,
                                                     int K, int N) {
    int idx = blockIdx.x * blockDim.x + threadIdx.x;
    if (idx >= K * N) return;
    int k = idx / N, n = idx - k * N;
    unsigned short h, l;
    split_hi_lo(W[idx], h, l);
    Bth[(size_t)n * K + k] = h;
    Btl[(size_t)n * K + k] = l;
}

// ---------------- LDS-staged 3-product MFMA GEMM ----------------
// (unchanged from R7 — verified, bit-identical numerics)
__global__ __launch_bounds__(256) void gemm_tile(const unsigned short* __restrict__ Ap,
                                                 const unsigned short* __restrict__ Bth,
                                                 const unsigned short* __restrict__ Btl,
                                                 unsigned short* __restrict__ C,
                                                 int M, int N) {
    __shared__ unsigned short lds[2][12288];
    const int tid = threadIdx.x;
    const int wave = tid >> 6, lane = tid & 63;
    const int r = lane & 15, b = lane >> 4;
    const int m0 = blockIdx.x * 128, n0 = blockIdx.y * 128;
    const int wrow = (wave & 1) * 64, wcol = (wave >> 1) * 64;

    f4v acc[4][4];
#pragma unroll
    for (int mf = 0; mf < 4; ++mf)
#pragma unroll
        for (int nf = 0; nf < 4; ++nf) acc[mf][nf] = (f4v){0.f, 0.f, 0.f, 0.f};

    auto stage = [&](int buf, int s) {
        char* lb = (char*)&lds[buf][0];
#pragma unroll
        for (int c = 0; c < 2; ++c) {
            int uni = c * 4096 + wave * 1024;        // wave-uniform dest offset
            int oc = uni + lane * 16;                // this lane's dest byte
            int row = oc >> 6;                       // tile row (64B per row)
            int cl = ((oc >> 4) & 3) ^ ((row >> 1) & 3);  // logical 16B chunk
            int arow = min(m0 + row, M - 1);
            gl_lds16(Ap + (size_t)arow * 512 + s * 32 + cl * 8, lb + uni);
            int bk = (s & 7) * 32 + cl * 8;
            const size_t boff = (size_t)(n0 + row) * 256 + bk;
            gl_lds16(Bth + boff, lb + 8192 + uni);
            if (s < 8) gl_lds16(Btl + boff, lb + 16384 + uni);
        }
    };

    stage(0, 0);
    __syncthreads();

    int buf = 0;
    for (int s = 0; s < 16; ++s) {
        if (s < 15) stage(buf ^ 1, s + 1);

        const char* lb = (const char*)&lds[buf][0];
        s8v af[4], bh[4], bl[4];
#pragma unroll
        for (int mf = 0; mf < 4; ++mf) {
            int trow = wrow + mf * 16 + r;
            int cp = b ^ ((trow >> 1) & 3);
            af[mf] = *reinterpret_cast<const s8v*>(lb + trow * 64 + cp * 16);
        }
#pragma unroll
        for (int nf = 0; nf < 4; ++nf) {
            int trow = wcol + nf * 16 + r;
            int cp = b ^ ((trow >> 1) & 3);
            bh[nf] = *reinterpret_cast<const s8v*>(lb + 8192 + trow * 64 + cp * 16);
            if (s < 8)
                bl[nf] = *reinterpret_cast<const s8v*>(lb + 16384 + trow * 64 + cp * 16);
        }
#pragma unroll
        for (int mf = 0; mf < 4; ++mf)
#pragma unroll
            for (int nf = 0; nf < 4; ++nf)
                acc[mf][nf] = __builtin_amdgcn_mfma_f32_16x16x32_bf16(af[mf], bh[nf], acc[mf][nf], 0, 0, 0);
        if (s < 8) {
#pragma unroll
            for (int mf = 0; mf < 4; ++mf)
#pragma unroll
                for (int nf = 0; nf < 4; ++nf)
                    acc[mf][nf] = __builtin_amdgcn_mfma_f32_16x16x32_bf16(af[mf], bl[nf], acc[mf][nf], 0, 0, 0);
        }
        __syncthreads();
        buf ^= 1;
    }

    // epilogue: D frag col = lane&15, row = 4*(lane>>4)+i  (m89/m91-verified)
#pragma unroll
    for (int mf = 0; mf < 4; ++mf)
#pragma unroll
        for (int i = 0; i < 4; ++i) {
            int grow = m0 + wrow + mf * 16 + b * 4 + i;
            if (grow < M) {
#pragma unroll
                for (int nf = 0; nf < 4; ++nf)
                    C[(size_t)grow * N + n0 + wcol + nf * 16 + r] =
                        (unsigned short)bf16_rne_bits(acc[mf][nf][i]);
            }
        }
}

// ---------------- CSR SpMM over bf16 X ----------------
// Wave per row; lane holds VEC=D/64 feats; 8x unrolled gathers; fp32 accum.
// SPLITOUT: relu -> [HAh|HAl] row-stride 512 into Ysplit. Else fp32 out.

template <int D, bool SPLITOUT>
__global__ __launch_bounds__(256) void spmm_bf16(const int* __restrict__ row_ptr,
                                                 const int2* __restrict__ meta,
                                                 const unsigned short* __restrict__ Xb,
                                                 float* __restrict__ Yo,
                                                 unsigned short* __restrict__ Ysplit,
                                                 int nrows) {
    constexpr int VEC = D / 64;  // 4 or 2
    const int lane = threadIdx.x & 63;
    const int wid = __builtin_amdgcn_readfirstlane(threadIdx.x >> 6);
    const int r = blockIdx.x * 4 + wid;
    if (r >= nrows) return;
    const int s = row_ptr[r];
    const int e = row_ptr[r + 1];
    const unsigned short* __restrict__ base = Xb + (size_t)lane * VEC;

    float acc[VEC];
#pragma unroll
    for (int k = 0; k < VEC; ++k) acc[k] = 0.f;

    int i = s;
    for (; i + 8 <= e; i += 8) {
        int2 mm[8];
#pragma unroll
        for (int u = 0; u < 8; ++u) mm[u] = meta[i + u];
        float xv[8][VEC];
#pragma unroll
        for (int u = 0; u < 8; ++u) {
            const unsigned short* p = base + (size_t)mm[u].x * D;
            if constexpr (VEC == 4) {
                uint2 t = *reinterpret_cast<const uint2*>(p);
                unpack2(t.x, xv[u][0], xv[u][1]);
                unpack2(t.y, xv[u][2], xv[u][3]);
            } else {
                unsigned int t = *reinterpret_cast<const unsigned int*>(p);
                unpack2(t, xv[u][0], xv[u][1]);
            }
        }
#pragma unroll
        for (int u = 0; u < 8; ++u) {
            float v = __int_as_float(mm[u].y);
#pragma unroll
            for (int k = 0; k < VEC; ++k) acc[k] = fmaf(v, xv[u][k], acc[k]);
        }
    }
    for (; i < e; ++i) {
        int2 m = meta[i];
        const unsigned short* p = base + (size_t)m.x * D;
        float xv[VEC];
        if constexpr (VEC == 4) {
            uint2 t = *reinterpret_cast<const uint2*>(p);
            unpack2(t.x, xv[0], xv[1]);
            unpack2(t.y, xv[2], xv[3]);
        } else {
            unsigned int t = *reinterpret_cast<const unsigned int*>(p);
            unpack2(t, xv[0], xv[1]);
        }
        float v = __int_as_float(m.y);
#pragma unroll
        for (int k = 0; k < VEC; ++k) acc[k] = fmaf(v, xv[k], acc[k]);
    }

    if constexpr (SPLITOUT) {
        static_assert(VEC == 4, "split path assumes D=256");
        ushort4 h, l;
        float a0 = fmaxf(acc[0], 0.f), a1 = fmaxf(acc[1], 0.f);
        float a2 = fmaxf(acc[2], 0.f), a3 = fmaxf(acc[3], 0.f);
        split_hi_lo(a0, h.x, l.x);
        split_hi_lo(a1, h.y, l.y);
        split_hi_lo(a2, h.z, l.z);
        split_hi_lo(a3, h.w, l.w);
        reinterpret_cast<ushort4*>(Ysplit + (size_t)r * 512)[lane] = h;
        reinterpret_cast<ushort4*>(Ysplit + (size_t)r * 512 + 256)[lane] = l;
    } else {
        float* yp = Yo + (size_t)r * D + lane * VEC;
        if constexpr (VEC == 4) {
            *reinterpret_cast<float4*>(yp) = make_float4(acc[0], acc[1], acc[2], acc[3]);
        } else {
            *reinterpret_cast<float2*>(yp) = make_float2(acc[0], acc[1]);
        }
    }
}

// ---------------- launch ----------------

extern "C" void kernel_launch(void* const* d_in, const int* in_sizes, int n_in,
                              void* d_out, int out_size, void* d_ws, size_t ws_size,
                              hipStream_t stream) {
    const float* Y     = (const float*)d_in[0];
    const int*   erow  = (const int*)d_in[1];
    const int*   ecol  = (const int*)d_in[2];
    const float* eval_ = (const float*)d_in[3];
    const float* W1    = (const float*)d_in[4];
    const float* W2    = (const float*)d_in[5];
    float* out = (float*)d_out;
    const int E = in_sizes[1];
    const int N = NN;

    // Workspace (~95 MB):
    //   [0, 51.2M)     Y' = [Yh|Yl]  (aliased as HA' after gemm1)
    //   [51.2, 76.8M)  Hb bf16 (reused as Gb)
    //   then W splits, row_ptr, cnt2d, bucket_base, brow, bcv, meta
    char* ws = (char*)d_ws;
    unsigned short* Yp = (unsigned short*)ws;
    unsigned short* Hb = (unsigned short*)(ws + 51200000);
    char* p = ws + 76800000;
    unsigned short* B1th = (unsigned short*)p; p += 131072;
    unsigned short* B1tl = (unsigned short*)p; p += 131072;
    unsigned short* B2th = (unsigned short*)p; p += 65536;
    unsigned short* B2tl = (unsigned short*)p; p += 65536;
    int* row_ptr     = (int*)p; p += 200064;             // (N+1)*4 padded
    int* cnt2d       = (int*)p; p += NBUCKET * PBLK * 4; // 800,768 B
    int* bucket_base = (int*)p; p += 1088;               // (NBUCKET+1)*4 padded
    int* brow        = (int*)p; p += 3200000;            // E*4
    int2* bcv        = (int2*)p; p += 6400000;           // E*8
    int2* meta       = (int2*)p;                         // E*8

    // CSR build — no global atomics
    bucket_hist<<<PBLK, 256, 0, stream>>>(erow, cnt2d, E);
    bucket_scan<<<1, 1024, 0, stream>>>(cnt2d, bucket_base, row_ptr, N, E);
    bucket_scatter<<<PBLK, 256, 0, stream>>>(erow, ecol, eval_, cnt2d, brow, bcv, E);
    bucket_build<<<NBUCKET, 256, 0, stream>>>(brow, bcv, bucket_base, row_ptr, meta, N);

    // Input splits
    split_kernel<<<2048, 256, 0, stream>>>(Y, Yp, N * 64);
    wsplit_kernel<<<256, 256, 0, stream>>>(W1, B1th, B1tl, 256, 256);
    wsplit_kernel<<<128, 256, 0, stream>>>(W2, B2th, B2tl, 256, 128);

    // Layer 1
    gemm_tile<<<dim3(391, 2), 256, 0, stream>>>(Yp, B1th, B1tl, Hb, N, 256);
    spmm_bf16<256, true><<<(N + 3) / 4, 256, 0, stream>>>(row_ptr, meta, Hb, nullptr, Yp, N);

    // Layer 2 (HA' aliases Yp; Gb aliases Hb)
    gemm_tile<<<dim3(391, 1), 256, 0, stream>>>(Yp, B2th, B2tl, Hb, N, 128);
    spmm_bf16<128, false><<<(N + 3) / 4, 256, 0, stream>>>(row_ptr, meta, Hb, out, nullptr, N);
}

// Round 10
// 299.561 us; speedup vs baseline: 2.0175x; 2.0175x over previous
//
#include <hip/hip_runtime.h>

// GCN 2-layer forward on MI355X (R10):
//   CSR build: atomic-free bucket partition; R9's serial 1-block scan
//   (325us!) replaced with a 3-kernel parallel scan (782x256 = 200192).
//   Hb  = bf16( Y@W1 )   LDS-staged MFMA GEMM, 3-product
//   HA' = relu(spmm(A,Hb)) -> [HAh|HAl]
//   Gb  = bf16( HA@W2 );  out = spmm(A,Gb)

#define NN 50000
#define NBUCKET 256
#define RPB 196          // rows per bucket (256*196 >= 50000)
#define PBLK 782         // partition blocks (782*1024 >= 800000 edges)

typedef short s8v __attribute__((ext_vector_type(8)));  // 8 bf16 in 4 VGPRs
typedef float f4v __attribute__((ext_vector_type(4)));
typedef unsigned int u32;

// ---------------- bf16 helpers ----------------

__device__ inline unsigned int bf16_rne_bits(float x) {
    unsigned int u = __float_as_uint(x);
    return (u + 0x7FFFu + ((u >> 16) & 1u)) >> 16;  // round-to-nearest-even
}
__device__ inline float bf16_bits_to_f32(unsigned int h) {
    return __uint_as_float(h << 16);
}
__device__ inline void split_hi_lo(float x, unsigned short& hi, unsigned short& lo) {
    unsigned int h = bf16_rne_bits(x);
    hi = (unsigned short)h;
    lo = (unsigned short)bf16_rne_bits(x - bf16_bits_to_f32(h));
}
__device__ inline void unpack2(unsigned int u, float& f0, float& f1) {
    f0 = __uint_as_float(u << 16);
    f1 = __uint_as_float(u & 0xFFFF0000u);
}

__device__ inline void gl_lds16(const void* g, void* l) {
    __builtin_amdgcn_global_load_lds(
        (const __attribute__((address_space(1))) u32*)g,
        (__attribute__((address_space(3))) u32*)l, 16, 0, 0);
}

// ---------------- CSR build: bucket partition (no global atomics) ----------------

// Per-block LDS histogram over 256 row-buckets -> cnt2d[bin][block].
__global__ __launch_bounds__(256) void bucket_hist(const int* __restrict__ erow,
                                                   int* __restrict__ cnt2d, int E) {
    __shared__ int h[NBUCKET];
    const int t = threadIdx.x, blk = blockIdx.x;
    h[t] = 0;
    __syncthreads();
#pragma unroll
    for (int u = 0; u < 4; ++u) {
        int i = blk * 1024 + u * 256 + t;
        if (i < E) atomicAdd(&h[erow[i] / RPB], 1);
    }
    __syncthreads();
    cnt2d[t * PBLK + blk] = h[t];
}

// --- 3-kernel parallel exclusive scan over cnt2d (NBUCKET*PBLK = 782*256) ---

__global__ __launch_bounds__(256) void pscan1(int* __restrict__ cnt2d,
                                              int* __restrict__ partial) {
    __shared__ int lds[256];
    const int t = threadIdx.x, b = blockIdx.x;
    const int i = b * 256 + t;
    int v = cnt2d[i];
    lds[t] = v;
    __syncthreads();
#pragma unroll
    for (int off = 1; off < 256; off <<= 1) {
        int a = (t >= off) ? lds[t - off] : 0;
        __syncthreads();
        lds[t] += a;
        __syncthreads();
    }
    cnt2d[i] = lds[t] - v;  // local exclusive
    if (t == 255) partial[b] = lds[255];
}

__global__ __launch_bounds__(1024) void pscan2(int* __restrict__ partial) {
    __shared__ int lds[1024];
    const int t = threadIdx.x;
    int v = (t < PBLK) ? partial[t] : 0;
    lds[t] = v;
    __syncthreads();
#pragma unroll
    for (int off = 1; off < 1024; off <<= 1) {
        int a = (t >= off) ? lds[t - off] : 0;
        __syncthreads();
        lds[t] += a;
        __syncthreads();
    }
    if (t < PBLK) partial[t] = lds[t] - v;  // exclusive block offsets
}

__global__ __launch_bounds__(256) void pscan3(int* __restrict__ cnt2d,
                                              const int* __restrict__ partial,
                                              int* __restrict__ bucket_base,
                                              int* __restrict__ row_ptr, int n, int E) {
    const int t = threadIdx.x, b = blockIdx.x;
    const int i = b * 256 + t;
    int val = cnt2d[i] + partial[b];
    cnt2d[i] = val;
    if (i % PBLK == 0) bucket_base[i / PBLK] = val;  // bucket start position
    if (i == 0) {
        bucket_base[NBUCKET] = E;
        row_ptr[n] = E;
    }
}

// Partition edges into bucket-contiguous brow/bcv using LDS cursors seeded
// from the scanned bases. No global atomics.
__global__ __launch_bounds__(256) void bucket_scatter(const int* __restrict__ erow,
                                                      const int* __restrict__ ecol,
                                                      const float* __restrict__ eval_,
                                                      const int* __restrict__ base2d,
                                                      int* __restrict__ brow,
                                                      int2* __restrict__ bcv, int E) {
    __shared__ int cur[NBUCKET];
    const int t = threadIdx.x, blk = blockIdx.x;
    cur[t] = base2d[t * PBLK + blk];
    __syncthreads();
#pragma unroll
    for (int u = 0; u < 4; ++u) {
        int i = blk * 1024 + u * 256 + t;
        if (i < E) {
            int r = erow[i];
            int pos = atomicAdd(&cur[r / RPB], 1);  // LDS atomic
            brow[pos] = r;
            bcv[pos] = make_int2(ecol[i], __float_as_int(eval_[i]));
        }
    }
}

// One block per bucket: LDS hist -> LDS scan -> row_ptr slice + meta scatter.
// All meta writes land in this bucket's contiguous ~25KB slice (one XCD).
__global__ __launch_bounds__(256) void bucket_build(const int* __restrict__ brow,
                                                    const int2* __restrict__ bcv,
                                                    const int* __restrict__ bucket_base,
                                                    int* __restrict__ row_ptr,
                                                    int2* __restrict__ meta, int n) {
    __shared__ int h[256];
    __shared__ int cur[256];
    const int t = threadIdx.x, b = blockIdx.x;
    const int s = bucket_base[b];
    const int e = bucket_base[b + 1];
    const int row0 = b * RPB;
    h[t] = 0;
    __syncthreads();
    for (int i = s + t; i < e; i += 256) atomicAdd(&h[brow[i] - row0], 1);
    __syncthreads();
    int v = h[t];
    for (int off = 1; off < 256; off <<= 1) {
        int a = (t >= off) ? h[t - off] : 0;
        __syncthreads();
        h[t] += a;
        __syncthreads();
    }
    int rp = s + h[t] - v;  // global exclusive position for row row0+t
    int grow = row0 + t;
    if (t < RPB && grow < n) row_ptr[grow] = rp;
    cur[t] = rp;
    __syncthreads();
    for (int i = s + t; i < e; i += 256) {
        int pos = atomicAdd(&cur[brow[i] - row0], 1);  // LDS atomic
        meta[pos] = bcv[i];
    }
}

// ---------------- split passes ----------------

// Y [M][256] f32 -> Y' [M][512] bf16 = [Yh(256) | Yl(256)]
__global__ __launch_bounds__(256) void split_kernel(const float* __restrict__ X,
                                                    unsigned short* __restrict__ Xp, int n4) {
    int i = blockIdx.x * blockDim.x + threadIdx.x;
    int stride = gridDim.x * blockDim.x;
    for (; i < n4; i += stride) {
        float4 v = reinterpret_cast<const float4*>(X)[i];
        ushort4 h, l;
        split_hi_lo(v.x, h.x, l.x);
        split_hi_lo(v.y, h.y, l.y);
        split_hi_lo(v.z, h.z, l.z);
        split_hi_lo(v.w, h.w, l.w);
        int row = i >> 6, c4 = (i & 63) * 4;
        *reinterpret_cast<ushort4*>(Xp + (size_t)row * 512 + c4) = h;
        *reinterpret_cast<ushort4*>(Xp + (size_t)row * 512 + 256 + c4) = l;
    }
}

// W [K=256][N] f32 -> Bth, Btl  [N][256] bf16 (transposed hi / lo)
__global__ __launch_bounds__(256) void wsplit_kernel(const float* __restrict__ W,
                                                     unsigned short* __restrict__ Bth,
                                                     unsigned short* __restrict__ Btl,
                                                     int K, int N) {
    int idx = blockIdx.x * blockDim.x + threadIdx.x;
    if (idx >= K * N) return;
    int k = idx / N, n = idx - k * N;
    unsigned short h, l;
    split_hi_lo(W[idx], h, l);
    Bth[(size_t)n * K + k] = h;
    Btl[(size_t)n * K + k] = l;
}

// ---------------- LDS-staged 3-product MFMA GEMM ----------------
// (unchanged from R7 — verified, bit-identical numerics)
__global__ __launch_bounds__(256) void gemm_tile(const unsigned short* __restrict__ Ap,
                                                 const unsigned short* __restrict__ Bth,
                                                 const unsigned short* __restrict__ Btl,
                                                 unsigned short* __restrict__ C,
                                                 int M, int N) {
    __shared__ unsigned short lds[2][12288];
    const int tid = threadIdx.x;
    const int wave = tid >> 6, lane = tid & 63;
    const int r = lane & 15, b = lane >> 4;
    const int m0 = blockIdx.x * 128, n0 = blockIdx.y * 128;
    const int wrow = (wave & 1) * 64, wcol = (wave >> 1) * 64;

    f4v acc[4][4];
#pragma unroll
    for (int mf = 0; mf < 4; ++mf)
#pragma unroll
        for (int nf = 0; nf < 4; ++nf) acc[mf][nf] = (f4v){0.f, 0.f, 0.f, 0.f};

    auto stage = [&](int buf, int s) {
        char* lb = (char*)&lds[buf][0];
#pragma unroll
        for (int c = 0; c < 2; ++c) {
            int uni = c * 4096 + wave * 1024;        // wave-uniform dest offset
            int oc = uni + lane * 16;                // this lane's dest byte
            int row = oc >> 6;                       // tile row (64B per row)
            int cl = ((oc >> 4) & 3) ^ ((row >> 1) & 3);  // logical 16B chunk
            int arow = min(m0 + row, M - 1);
            gl_lds16(Ap + (size_t)arow * 512 + s * 32 + cl * 8, lb + uni);
            int bk = (s & 7) * 32 + cl * 8;
            const size_t boff = (size_t)(n0 + row) * 256 + bk;
            gl_lds16(Bth + boff, lb + 8192 + uni);
            if (s < 8) gl_lds16(Btl + boff, lb + 16384 + uni);
        }
    };

    stage(0, 0);
    __syncthreads();

    int buf = 0;
    for (int s = 0; s < 16; ++s) {
        if (s < 15) stage(buf ^ 1, s + 1);

        const char* lb = (const char*)&lds[buf][0];
        s8v af[4], bh[4], bl[4];
#pragma unroll
        for (int mf = 0; mf < 4; ++mf) {
            int trow = wrow + mf * 16 + r;
            int cp = b ^ ((trow >> 1) & 3);
            af[mf] = *reinterpret_cast<const s8v*>(lb + trow * 64 + cp * 16);
        }
#pragma unroll
        for (int nf = 0; nf < 4; ++nf) {
            int trow = wcol + nf * 16 + r;
            int cp = b ^ ((trow >> 1) & 3);
            bh[nf] = *reinterpret_cast<const s8v*>(lb + 8192 + trow * 64 + cp * 16);
            if (s < 8)
                bl[nf] = *reinterpret_cast<const s8v*>(lb + 16384 + trow * 64 + cp * 16);
        }
#pragma unroll
        for (int mf = 0; mf < 4; ++mf)
#pragma unroll
            for (int nf = 0; nf < 4; ++nf)
                acc[mf][nf] = __builtin_amdgcn_mfma_f32_16x16x32_bf16(af[mf], bh[nf], acc[mf][nf], 0, 0, 0);
        if (s < 8) {
#pragma unroll
            for (int mf = 0; mf < 4; ++mf)
#pragma unroll
                for (int nf = 0; nf < 4; ++nf)
                    acc[mf][nf] = __builtin_amdgcn_mfma_f32_16x16x32_bf16(af[mf], bl[nf], acc[mf][nf], 0, 0, 0);
        }
        __syncthreads();
        buf ^= 1;
    }

    // epilogue: D frag col = lane&15, row = 4*(lane>>4)+i  (m89/m91-verified)
#pragma unroll
    for (int mf = 0; mf < 4; ++mf)
#pragma unroll
        for (int i = 0; i < 4; ++i) {
            int grow = m0 + wrow + mf * 16 + b * 4 + i;
            if (grow < M) {
#pragma unroll
                for (int nf = 0; nf < 4; ++nf)
                    C[(size_t)grow * N + n0 + wcol + nf * 16 + r] =
                        (unsigned short)bf16_rne_bits(acc[mf][nf][i]);
            }
        }
}

// ---------------- CSR SpMM over bf16 X ----------------
// Wave per row; lane holds VEC=D/64 feats; 8x unrolled gathers; fp32 accum.
// SPLITOUT: relu -> [HAh|HAl] row-stride 512 into Ysplit. Else fp32 out.

template <int D, bool SPLITOUT>
__global__ __launch_bounds__(256) void spmm_bf16(const int* __restrict__ row_ptr,
                                                 const int2* __restrict__ meta,
                                                 const unsigned short* __restrict__ Xb,
                                                 float* __restrict__ Yo,
                                                 unsigned short* __restrict__ Ysplit,
                                                 int nrows) {
    constexpr int VEC = D / 64;  // 4 or 2
    const int lane = threadIdx.x & 63;
    const int wid = __builtin_amdgcn_readfirstlane(threadIdx.x >> 6);
    const int r = blockIdx.x * 4 + wid;
    if (r >= nrows) return;
    const int s = row_ptr[r];
    const int e = row_ptr[r + 1];
    const unsigned short* __restrict__ base = Xb + (size_t)lane * VEC;

    float acc[VEC];
#pragma unroll
    for (int k = 0; k < VEC; ++k) acc[k] = 0.f;

    int i = s;
    for (; i + 8 <= e; i += 8) {
        int2 mm[8];
#pragma unroll
        for (int u = 0; u < 8; ++u) mm[u] = meta[i + u];
        float xv[8][VEC];
#pragma unroll
        for (int u = 0; u < 8; ++u) {
            const unsigned short* p = base + (size_t)mm[u].x * D;
            if constexpr (VEC == 4) {
                uint2 t = *reinterpret_cast<const uint2*>(p);
                unpack2(t.x, xv[u][0], xv[u][1]);
                unpack2(t.y, xv[u][2], xv[u][3]);
            } else {
                unsigned int t = *reinterpret_cast<const unsigned int*>(p);
                unpack2(t, xv[u][0], xv[u][1]);
            }
        }
#pragma unroll
        for (int u = 0; u < 8; ++u) {
            float v = __int_as_float(mm[u].y);
#pragma unroll
            for (int k = 0; k < VEC; ++k) acc[k] = fmaf(v, xv[u][k], acc[k]);
        }
    }
    for (; i < e; ++i) {
        int2 m = meta[i];
        const unsigned short* p = base + (size_t)m.x * D;
        float xv[VEC];
        if constexpr (VEC == 4) {
            uint2 t = *reinterpret_cast<const uint2*>(p);
            unpack2(t.x, xv[0], xv[1]);
            unpack2(t.y, xv[2], xv[3]);
        } else {
            unsigned int t = *reinterpret_cast<const unsigned int*>(p);
            unpack2(t, xv[0], xv[1]);
        }
        float v = __int_as_float(m.y);
#pragma unroll
        for (int k = 0; k < VEC; ++k) acc[k] = fmaf(v, xv[k], acc[k]);
    }

    if constexpr (SPLITOUT) {
        static_assert(VEC == 4, "split path assumes D=256");
        ushort4 h, l;
        float a0 = fmaxf(acc[0], 0.f), a1 = fmaxf(acc[1], 0.f);
        float a2 = fmaxf(acc[2], 0.f), a3 = fmaxf(acc[3], 0.f);
        split_hi_lo(a0, h.x, l.x);
        split_hi_lo(a1, h.y, l.y);
        split_hi_lo(a2, h.z, l.z);
        split_hi_lo(a3, h.w, l.w);
        reinterpret_cast<ushort4*>(Ysplit + (size_t)r * 512)[lane] = h;
        reinterpret_cast<ushort4*>(Ysplit + (size_t)r * 512 + 256)[lane] = l;
    } else {
        float* yp = Yo + (size_t)r * D + lane * VEC;
        if constexpr (VEC == 4) {
            *reinterpret_cast<float4*>(yp) = make_float4(acc[0], acc[1], acc[2], acc[3]);
        } else {
            *reinterpret_cast<float2*>(yp) = make_float2(acc[0], acc[1]);
        }
    }
}

// ---------------- launch ----------------

extern "C" void kernel_launch(void* const* d_in, const int* in_sizes, int n_in,
                              void* d_out, int out_size, void* d_ws, size_t ws_size,
                              hipStream_t stream) {
    const float* Y     = (const float*)d_in[0];
    const int*   erow  = (const int*)d_in[1];
    const int*   ecol  = (const int*)d_in[2];
    const float* eval_ = (const float*)d_in[3];
    const float* W1    = (const float*)d_in[4];
    const float* W2    = (const float*)d_in[5];
    float* out = (float*)d_out;
    const int E = in_sizes[1];
    const int N = NN;

    // Workspace (~95 MB):
    //   [0, 51.2M)     Y' = [Yh|Yl]  (aliased as HA' after gemm1)
    //   [51.2, 76.8M)  Hb bf16 (reused as Gb)
    //   then W splits, row_ptr, cnt2d, partial, bucket_base, brow, bcv, meta
    char* ws = (char*)d_ws;
    unsigned short* Yp = (unsigned short*)ws;
    unsigned short* Hb = (unsigned short*)(ws + 51200000);
    char* p = ws + 76800000;
    unsigned short* B1th = (unsigned short*)p; p += 131072;
    unsigned short* B1tl = (unsigned short*)p; p += 131072;
    unsigned short* B2th = (unsigned short*)p; p += 65536;
    unsigned short* B2tl = (unsigned short*)p; p += 65536;
    int* row_ptr     = (int*)p; p += 200064;             // (N+1)*4 padded
    int* cnt2d       = (int*)p; p += NBUCKET * PBLK * 4; // 800,768 B
    int* partial     = (int*)p; p += 4096;               // PBLK*4 padded
    int* bucket_base = (int*)p; p += 1088;               // (NBUCKET+1)*4 padded
    int* brow        = (int*)p; p += 3200000;            // E*4
    int2* bcv        = (int2*)p; p += 6400000;           // E*8
    int2* meta       = (int2*)p;                         // E*8

    // CSR build — no global atomics, fully parallel scan
    bucket_hist<<<PBLK, 256, 0, stream>>>(erow, cnt2d, E);
    pscan1<<<PBLK, 256, 0, stream>>>(cnt2d, partial);
    pscan2<<<1, 1024, 0, stream>>>(partial);
    pscan3<<<PBLK, 256, 0, stream>>>(cnt2d, partial, bucket_base, row_ptr, N, E);
    bucket_scatter<<<PBLK, 256, 0, stream>>>(erow, ecol, eval_, cnt2d, brow, bcv, E);
    bucket_build<<<NBUCKET, 256, 0, stream>>>(brow, bcv, bucket_base, row_ptr, meta, N);

    // Input splits
    split_kernel<<<2048, 256, 0, stream>>>(Y, Yp, N * 64);
    wsplit_kernel<<<256, 256, 0, stream>>>(W1, B1th, B1tl, 256, 256);
    wsplit_kernel<<<128, 256, 0, stream>>>(W2, B2th, B2tl, 256, 128);

    // Layer 1
    gemm_tile<<<dim3(391, 2), 256, 0, stream>>>(Yp, B1th, B1tl, Hb, N, 256);
    spmm_bf16<256, true><<<(N + 3) / 4, 256, 0, stream>>>(row_ptr, meta, Hb, nullptr, Yp, N);

    // Layer 2 (HA' aliases Yp; Gb aliases Hb)
    gemm_tile<<<dim3(391, 1), 256, 0, stream>>>(Yp, B2th, B2tl, Hb, N, 128);
    spmm_bf16<128, false><<<(N + 3) / 4, 256, 0, stream>>>(row_ptr, meta, Hb, out, nullptr, N);
}